// Round 2
// baseline (128.652 us; speedup 1.0000x reference)
//
#include <hip/hip_runtime.h>

// out = relu((x @ B^T) * A^T + bias)  -- rank-1 reassociated form.
// x: [8192, 2048] f32, A: [10000,1] f32, B: [1,2048] f32, bias: [10000] f32
// out: [8192, 10000] f32
//
// Split: K1 computes s = x @ B^T into d_ws (read-bound, 67 MB).
//        K2 streams out = relu(s*A+bias) (write-bound, 328 MB), A/bias in
//        registers per column-chunk, s staged in LDS per 32-row group.

#define BATCH       8192
#define IN_FEATURES 2048
#define N_CLASSES   10000
#define NC4         (N_CLASSES / 4)   // 2500, exact
#define BLOCK       256
#define ROWS_PER_BLK 32               // K2 row-group size

// ---------------- K1: s[row] = dot(x[row,:], B[0,:]) ----------------
__global__ __launch_bounds__(BLOCK) void lora_dot_kernel(
    const float* __restrict__ x,
    const float* __restrict__ B,
    float* __restrict__ s_out)
{
    const int row = blockIdx.x;
    const int tid = threadIdx.x;

    const float4* __restrict__ x4 = reinterpret_cast<const float4*>(x + (size_t)row * IN_FEATURES);
    const float4* __restrict__ B4 = reinterpret_cast<const float4*>(B);

    float acc = 0.0f;
    // 512 float4 per row / 256 threads = 2 per thread (coalesced)
    float4 xa = x4[tid];
    float4 ba = B4[tid];
    float4 xb = x4[tid + BLOCK];
    float4 bb = B4[tid + BLOCK];
    acc = fmaf(xa.x, ba.x, acc);
    acc = fmaf(xa.y, ba.y, acc);
    acc = fmaf(xa.z, ba.z, acc);
    acc = fmaf(xa.w, ba.w, acc);
    acc = fmaf(xb.x, bb.x, acc);
    acc = fmaf(xb.y, bb.y, acc);
    acc = fmaf(xb.z, bb.z, acc);
    acc = fmaf(xb.w, bb.w, acc);

    #pragma unroll
    for (int off = 32; off > 0; off >>= 1)
        acc += __shfl_down(acc, off, 64);

    __shared__ float wsum[BLOCK / 64];
    const int lane = tid & 63;
    const int wid  = tid >> 6;
    if (lane == 0) wsum[wid] = acc;
    __syncthreads();
    if (tid == 0)
        s_out[row] = wsum[0] + wsum[1] + wsum[2] + wsum[3];
}

// ---------------- K2: out[r, j] = relu(s[r]*A[j] + bias[j]) ----------------
// grid.x = column-chunks (10 x 256 f4-cols), grid.y = row groups (8192/32)
__global__ __launch_bounds__(BLOCK) void lora_bcast_kernel(
    const float* __restrict__ s_vec,
    const float* __restrict__ A,
    const float* __restrict__ bias,
    float* __restrict__ out)
{
    const int tid  = threadIdx.x;
    const int col4 = blockIdx.x * BLOCK + tid;     // float4 column index
    const int row0 = blockIdx.y * ROWS_PER_BLK;

    __shared__ float s_lds[ROWS_PER_BLK];
    if (tid < ROWS_PER_BLK) s_lds[tid] = s_vec[row0 + tid];
    __syncthreads();

    if (col4 >= NC4) return;

    const float4 a = reinterpret_cast<const float4*>(A)[col4];
    const float4 b = reinterpret_cast<const float4*>(bias)[col4];

    float4* __restrict__ o4 = reinterpret_cast<float4*>(out) + (size_t)row0 * NC4 + col4;

    #pragma unroll 8
    for (int r = 0; r < ROWS_PER_BLK; ++r) {
        const float s = s_lds[r];
        float4 v;
        v.x = fmaxf(fmaf(s, a.x, b.x), 0.0f);
        v.y = fmaxf(fmaf(s, a.y, b.y), 0.0f);
        v.z = fmaxf(fmaf(s, a.z, b.z), 0.0f);
        v.w = fmaxf(fmaf(s, a.w, b.w), 0.0f);
        o4[(size_t)r * NC4] = v;
    }
}

extern "C" void kernel_launch(void* const* d_in, const int* in_sizes, int n_in,
                              void* d_out, int out_size, void* d_ws, size_t ws_size,
                              hipStream_t stream) {
    const float* x    = (const float*)d_in[0];
    const float* A    = (const float*)d_in[1];
    const float* B    = (const float*)d_in[2];
    const float* bias = (const float*)d_in[3];
    float* out        = (float*)d_out;
    float* s_vec      = (float*)d_ws;   // 8192 floats

    lora_dot_kernel<<<BATCH, BLOCK, 0, stream>>>(x, B, s_vec);

    dim3 grid((NC4 + BLOCK - 1) / BLOCK, BATCH / ROWS_PER_BLK);  // (10, 256)
    lora_bcast_kernel<<<grid, BLOCK, 0, stream>>>(s_vec, A, bias, out);
}

// Round 4
// 69.546 us; speedup vs baseline: 1.8499x; 1.8499x over previous
//
#include <hip/hip_runtime.h>

// out = relu((x @ B^T) * A^T + bias)  -- rank-1 reassociated form.
// x: [8192, 2048] f32, A: [10000,1] f32, B: [1,2048] f32, bias: [10000] f32
// out: [8192, 10000] f32
//
// Fused single kernel, 2 rows per block. Output stores are NONTEMPORAL
// (bypass L2 allocate) -- theory: streaming 328MB through the 4MiB/XCD
// write-back L2 was halving effective write BW.
// NOTE: __builtin_nontemporal_store needs a clang ext_vector_type, not
// HIP_vector_type (float4) -- hence fx4 below.

#define BATCH       8192
#define IN_FEATURES 2048
#define N_CLASSES   10000
#define NC4         (N_CLASSES / 4)   // 2500
#define BLOCK       256
#define RPB         2                 // rows per block

typedef float fx4 __attribute__((ext_vector_type(4)));

__global__ __launch_bounds__(BLOCK) void lora_fused2_kernel(
    const float* __restrict__ x,
    const float* __restrict__ A,
    const float* __restrict__ B,
    const float* __restrict__ bias,
    float* __restrict__ out)
{
    const int tid  = threadIdx.x;
    const int row0 = blockIdx.x * RPB;

    // ---- Phase 1: s0 = dot(x[row0,:],B), s1 = dot(x[row0+1,:],B) ----
    const fx4* __restrict__ x40 = reinterpret_cast<const fx4*>(x + (size_t)row0 * IN_FEATURES);
    const fx4* __restrict__ x41 = reinterpret_cast<const fx4*>(x + (size_t)(row0 + 1) * IN_FEATURES);
    const fx4* __restrict__ B4  = reinterpret_cast<const fx4*>(B);

    fx4 ba  = B4[tid];
    fx4 bb  = B4[tid + BLOCK];
    fx4 xa0 = x40[tid];
    fx4 xb0 = x40[tid + BLOCK];
    fx4 xa1 = x41[tid];
    fx4 xb1 = x41[tid + BLOCK];

    float acc0 = 0.0f, acc1 = 0.0f;
    acc0 = fmaf(xa0.x, ba.x, acc0);  acc1 = fmaf(xa1.x, ba.x, acc1);
    acc0 = fmaf(xa0.y, ba.y, acc0);  acc1 = fmaf(xa1.y, ba.y, acc1);
    acc0 = fmaf(xa0.z, ba.z, acc0);  acc1 = fmaf(xa1.z, ba.z, acc1);
    acc0 = fmaf(xa0.w, ba.w, acc0);  acc1 = fmaf(xa1.w, ba.w, acc1);
    acc0 = fmaf(xb0.x, bb.x, acc0);  acc1 = fmaf(xb1.x, bb.x, acc1);
    acc0 = fmaf(xb0.y, bb.y, acc0);  acc1 = fmaf(xb1.y, bb.y, acc1);
    acc0 = fmaf(xb0.z, bb.z, acc0);  acc1 = fmaf(xb1.z, bb.z, acc1);
    acc0 = fmaf(xb0.w, bb.w, acc0);  acc1 = fmaf(xb1.w, bb.w, acc1);

    #pragma unroll
    for (int off = 32; off > 0; off >>= 1) {
        acc0 += __shfl_down(acc0, off, 64);
        acc1 += __shfl_down(acc1, off, 64);
    }

    __shared__ float wsum0[BLOCK / 64];
    __shared__ float wsum1[BLOCK / 64];
    __shared__ float sb[2];
    const int lane = tid & 63;
    const int wid  = tid >> 6;
    if (lane == 0) { wsum0[wid] = acc0; wsum1[wid] = acc1; }
    __syncthreads();
    if (tid == 0) sb[0] = wsum0[0] + wsum0[1] + wsum0[2] + wsum0[3];
    if (tid == 1) sb[1] = wsum1[0] + wsum1[1] + wsum1[2] + wsum1[3];
    __syncthreads();
    const float s0 = sb[0];
    const float s1 = sb[1];

    // ---- Phase 2: out[row, j] = relu(s * A[j] + bias[j]), nontemporal ----
    const fx4* __restrict__ A4  = reinterpret_cast<const fx4*>(A);
    const fx4* __restrict__ bb4 = reinterpret_cast<const fx4*>(bias);
    fx4* __restrict__ o0 = reinterpret_cast<fx4*>(out) + (size_t)row0 * NC4;
    fx4* __restrict__ o1 = o0 + NC4;

    for (int j = tid; j < NC4; j += BLOCK) {
        fx4 a = A4[j];
        fx4 b = bb4[j];
        fx4 v0, v1;
        v0.x = fmaxf(fmaf(s0, a.x, b.x), 0.0f);
        v0.y = fmaxf(fmaf(s0, a.y, b.y), 0.0f);
        v0.z = fmaxf(fmaf(s0, a.z, b.z), 0.0f);
        v0.w = fmaxf(fmaf(s0, a.w, b.w), 0.0f);
        v1.x = fmaxf(fmaf(s1, a.x, b.x), 0.0f);
        v1.y = fmaxf(fmaf(s1, a.y, b.y), 0.0f);
        v1.z = fmaxf(fmaf(s1, a.z, b.z), 0.0f);
        v1.w = fmaxf(fmaf(s1, a.w, b.w), 0.0f);
        __builtin_nontemporal_store(v0, &o0[j]);
        __builtin_nontemporal_store(v1, &o1[j]);
    }
}

extern "C" void kernel_launch(void* const* d_in, const int* in_sizes, int n_in,
                              void* d_out, int out_size, void* d_ws, size_t ws_size,
                              hipStream_t stream) {
    const float* x    = (const float*)d_in[0];
    const float* A    = (const float*)d_in[1];
    const float* B    = (const float*)d_in[2];
    const float* bias = (const float*)d_in[3];
    float* out        = (float*)d_out;

    lora_fused2_kernel<<<BATCH / RPB, BLOCK, 0, stream>>>(x, A, B, bias, out);
}